// Round 1
// baseline (182.904 us; speedup 1.0000x reference)
//
#include <hip/hip_runtime.h>
#include <hip/hip_bf16.h>

// 12-qubit statevector simulator, fp32, LDS-resident.
// Kernel 1: one block per (b,t): encode + K/V projections (+Q at t=63),
//           writes 12-dim features to ws.
// Kernel 2: attention last-row + MLP -> d_out (8x4 fp32).

#define PADDED 4224  // 4096 + 4096/32 padding

__device__ __forceinline__ int PD(int j) { return j + (j >> 5); }

// mode 0: identity; 1: encode ladder+ring read map; 2: CX_LONG; 3: ladder only
__device__ __forceinline__ int mapIdx(int j, int mode) {
  if (mode == 1) { int k = j ^ ((j >> 11) & 1); return k ^ ((k & 0x7FF) << 1); }
  if (mode == 2) { return j ^ ((j & 1) << 11); }
  if (mode == 3) { return j ^ ((j & 0x7FF) << 1); }
  return j;
}

template <int L>
__device__ __forceinline__ int layoutIdx(int tid, int r) {
  if constexpr (L == 0) return (tid << 4) | r;                                  // bits 0-3 local
  else if constexpr (L == 1) return ((tid & 0xF0) << 4) | (r << 4) | (tid & 15); // bits 4-7 local
  else return (r << 8) | tid;                                                    // bits 8-11 local
}

template <int L>
__device__ __forceinline__ void ldsRead16(const float* sR, const float* sI, int tid, int mode,
                                          float ar[16], float ai[16]) {
#pragma unroll
  for (int r = 0; r < 16; ++r) {
    int j = layoutIdx<L>(tid, r);
    int a = PD(mapIdx(j, mode));
    ar[r] = sR[a]; ai[r] = sI[a];
  }
}

template <int L>
__device__ __forceinline__ void ldsWrite16(float* sR, float* sI, int tid,
                                           const float ar[16], const float ai[16], int czmask) {
#pragma unroll
  for (int r = 0; r < 16; ++r) {
    int j = layoutIdx<L>(tid, r);
    float vr = ar[r], vi = ai[r];
    if (czmask) {
      float sg = (__popc((j & (j >> 1)) & czmask) & 1) ? -1.0f : 1.0f;
      vr *= sg; vi *= sg;
    }
    int a = PD(j);
    sR[a] = vr; sI[a] = vi;
  }
}

// 4 U3 gates on local bits 0..3 (ut[b] = {u00r,u00i,u01r,u01i,u10r,u10i,u11r,u11i})
__device__ __forceinline__ void applyU34(float ar[16], float ai[16], const float (*ut)[8]) {
#pragma unroll
  for (int b = 0; b < 4; ++b) {
    const float* u = ut[b];
    float u00r = u[0], u00i = u[1], u01r = u[2], u01i = u[3];
    float u10r = u[4], u10i = u[5], u11r = u[6], u11i = u[7];
#pragma unroll
    for (int m = 0; m < 8; ++m) {
      int p0 = ((m >> b) << (b + 1)) | (m & ((1 << b) - 1));
      int p1 = p0 | (1 << b);
      float x0r = ar[p0], x0i = ai[p0], x1r = ar[p1], x1i = ai[p1];
      ar[p0] = u00r * x0r - u00i * x0i + u01r * x1r - u01i * x1i;
      ai[p0] = u00r * x0i + u00i * x0r + u01r * x1i + u01i * x1r;
      ar[p1] = u10r * x0r - u10i * x0i + u11r * x1r - u11i * x1i;
      ai[p1] = u10r * x0i + u10i * x0r + u11r * x1i + u11i * x1r;
    }
  }
}

// 4 fused RY+RZ gates on local bits 0..3 (gt[b] = {cos t/2, sin t/2, cos p/2, sin p/2})
__device__ __forceinline__ void applyRyRz4(float ar[16], float ai[16], const float4* gt) {
#pragma unroll
  for (int b = 0; b < 4; ++b) {
    float4 g = gt[b];
    float c = g.x, s = g.y, zr = g.z, zi = g.w;
#pragma unroll
    for (int m = 0; m < 8; ++m) {
      int p0 = ((m >> b) << (b + 1)) | (m & ((1 << b) - 1));
      int p1 = p0 | (1 << b);
      float n0r = c * ar[p0] - s * ar[p1];
      float n0i = c * ai[p0] - s * ai[p1];
      float n1r = s * ar[p0] + c * ar[p1];
      float n1i = s * ai[p0] + c * ai[p1];
      // amp0 *= e^{-i p/2}; amp1 *= e^{+i p/2}
      ar[p0] = n0r * zr + n0i * zi;  ai[p0] = n0i * zr - n0r * zi;
      ar[p1] = n1r * zr - n1i * zi;  ai[p1] = n1i * zr + n1r * zi;
    }
  }
}

template <int L>
__device__ __forceinline__ void encPass(float* sR, float* sI, int tid, int mode,
                                        const float (*ut)[8], int czmask) {
  float ar[16], ai[16];
  ldsRead16<L>(sR, sI, tid, mode, ar, ai);
  if (mode != 0) __syncthreads();   // perm reads cross thread sets: drain before writes
  applyU34(ar, ai, ut);
  ldsWrite16<L>(sR, sI, tid, ar, ai, czmask);
  __syncthreads();
}

template <int L>
__device__ __forceinline__ void projPass(float* sR, float* sI, int tid, int mode, const float4* gt) {
  float ar[16], ai[16];
  ldsRead16<L>(sR, sI, tid, mode, ar, ai);
  if (mode != 0) __syncthreads();
  applyRyRz4(ar, ai, gt);
  ldsWrite16<L>(sR, sI, tid, ar, ai, 0);
  __syncthreads();
}

// Final projection pass: gates on qubits 8-11 of layer 1, then fold the trailing
// CX ladder into the Z-sign via M^{-1} = prefix-XOR; accumulate 12 features.
__device__ __forceinline__ void projFinal(const float* sR, const float* sI, int tid,
                                          const float4* gt, float feat[12]) {
  float ar[16], ai[16];
#pragma unroll
  for (int r = 0; r < 16; ++r) {
    int a = PD((r << 8) | tid);
    ar[r] = sR[a]; ai[r] = sI[a];
  }
  applyRyRz4(ar, ai, gt);
  float sp = 0.f, f0 = 0.f, f1 = 0.f, f2 = 0.f, f3 = 0.f;
  int pt = __popc(tid) & 1;  // parity of j bits 0..7
#pragma unroll
  for (int r = 0; r < 16; ++r) {
    float p = ar[r] * ar[r] + ai[r] * ai[r];
    sp += p;
    int tr = r ^ (r << 1); tr ^= (tr << 2);  // 4-bit prefix-xor of r
    f0 += ((pt ^ ((tr >> 3) & 1)) ? -p : p);
    f1 += ((pt ^ ((tr >> 2) & 1)) ? -p : p);
    f2 += ((pt ^ ((tr >> 1) & 1)) ? -p : p);
    f3 += ((pt ^ (tr & 1)) ? -p : p);
  }
  feat[0] = f0; feat[1] = f1; feat[2] = f2; feat[3] = f3;
  int tt = tid ^ (tid << 1); tt ^= (tt << 2); tt ^= (tt << 4);  // 8-bit prefix-xor of tid
#pragma unroll
  for (int q = 4; q < 12; ++q)
    feat[q] = ((tt >> (11 - q)) & 1) ? -sp : sp;
}

__device__ __forceinline__ float waveReduce(float v) {
#pragma unroll
  for (int off = 32; off; off >>= 1) v += __shfl_xor(v, off, 64);
  return v;
}

__global__ __launch_bounds__(256, 2) void qstates_kernel(
    const float* __restrict__ seq, const float* __restrict__ resp,
    const float* __restrict__ hparams, float* __restrict__ ws) {
  __shared__ float sRe[PADDED], sIm[PADDED];
  __shared__ float4 qtab[12];     // per-qubit init amps (a0r,a0i,a1r,a1i)
  __shared__ float utab[36][8];   // U3 gates, 3 layers x 12 qubits
  __shared__ float4 ptab[24];     // projection RY/RZ, 2 layers x 12 qubits
  __shared__ float red[4][12];

  const int tid = threadIdx.x;
  const int blk = blockIdx.x;
  const int b = blk >> 6;
  const int t = blk & 63;
  const float x = seq[(b << 6) | t];
  const float PI = 3.14159265358979323846f;
  const float RS2 = 0.70710678118654752440f;

  if (tid < 12) {
    int i = tid;
    float th = x * PI * (float)(i + 1) / 12.0f;
    float ph = x * PI / (float)(i + 1);
    float s, c;  sincosf(0.5f * th, &s, &c);
    float zi, zr; sincosf(0.5f * ph, &zi, &zr);
    float k0 = (c - s) * RS2, k1 = (c + s) * RS2;
    qtab[i] = make_float4(k0 * zr, -k0 * zi, k1 * zr, k1 * zi);
  }
  if (tid >= 64 && tid < 100) {
    int i = tid - 64;
    const float* rp = resp + i * 3;
    float st, ct;  sincosf(0.5f * rp[0], &st, &ct);
    float sp2, cp; sincosf(rp[1], &sp2, &cp);
    float sl, cl;  sincosf(rp[2], &sl, &cl);
    float spl, cpl; sincosf(rp[1] + rp[2], &spl, &cpl);
    float* u = utab[i];
    u[0] = ct;       u[1] = 0.0f;
    u[2] = -cl * st; u[3] = -sl * st;
    u[4] = cp * st;  u[5] = sp2 * st;
    u[6] = cpl * ct; u[7] = spl * ct;
  }
  __syncthreads();

  // E0: product state directly (init RY/RZ are all single-qubit on |+>^12)
  {
    float pr, pi;
    {
      float4 g = qtab[4];
      int sb = tid & 1;
      pr = sb ? g.z : g.x; pi = sb ? g.w : g.y;
    }
#pragma unroll
    for (int q = 5; q < 12; ++q) {
      float4 g = qtab[q];
      int sb = (tid >> (q - 4)) & 1;
      float fr = sb ? g.z : g.x, fi = sb ? g.w : g.y;
      float nr = pr * fr - pi * fi;
      pi = pr * fi + pi * fr; pr = nr;
    }
    float4 g0 = qtab[0], g1 = qtab[1], g2 = qtab[2], g3 = qtab[3];
    float c01r[4], c01i[4], c23r[4], c23i[4];
#pragma unroll
    for (int i2 = 0; i2 < 4; ++i2) {
      float f0r = (i2 & 1) ? g0.z : g0.x, f0i = (i2 & 1) ? g0.w : g0.y;
      float f1r = (i2 & 2) ? g1.z : g1.x, f1i = (i2 & 2) ? g1.w : g1.y;
      c01r[i2] = f0r * f1r - f0i * f1i; c01i[i2] = f0r * f1i + f0i * f1r;
      float f2r = (i2 & 1) ? g2.z : g2.x, f2i = (i2 & 1) ? g2.w : g2.y;
      float f3r = (i2 & 2) ? g3.z : g3.x, f3i = (i2 & 2) ? g3.w : g3.y;
      c23r[i2] = f2r * f3r - f2i * f3i; c23i[i2] = f2r * f3i + f2i * f3r;
    }
#pragma unroll
    for (int r = 0; r < 16; ++r) {
      float lr = c01r[r & 3] * c23r[r >> 2] - c01i[r & 3] * c23i[r >> 2];
      float li = c01r[r & 3] * c23i[r >> 2] + c01i[r & 3] * c23r[r >> 2];
      int a = PD((tid << 4) | r);
      sRe[a] = pr * lr - pi * li;
      sIm[a] = pr * li + pi * lr;
    }
  }
  __syncthreads();

  // Encode: 3 layers of 12 U3 + CZ; perms folded into read maps
  for (int l = 0; l < 3; ++l) {
    int czm = (l & 1) ? 0x2AA : 0x555;
    encPass<0>(sRe, sIm, tid, (l == 0) ? 1 : 2, &utab[l * 12], 0);
    encPass<1>(sRe, sIm, tid, 0, &utab[l * 12 + 4], 0);
    encPass<2>(sRe, sIm, tid, 0, &utab[l * 12 + 8], czm);
  }

  // Cache encoded state in regs (trailing CX_LONG folded into read)
  float encR[16], encI[16];
#pragma unroll
  for (int r = 0; r < 16; ++r) {
    int j = (tid << 4) | r;
    int a = PD(j ^ ((j & 1) << 11));
    encR[r] = sRe[a]; encI[r] = sIm[a];
  }

  float* wsK = ws;
  float* wsV = ws + 12288;
  float* wsQ = ws + 24576;

  const int nproj = (t == 63) ? 6 : 4;
  for (int pj = 0; pj < nproj; ++pj) {
    int h, which;  // which: 0=Q,1=K,2=V
    if (pj < 4) { h = pj >> 1; which = (pj & 1) ? 2 : 1; }
    else        { h = pj - 4;  which = 0; }
    const float* hp = hparams + (h * 3 + which) * 48;
    if (tid < 24) {
      int k = tid * 2;
      float s, c;  sincosf(0.5f * hp[k], &s, &c);
      float zi, zr; sincosf(0.5f * hp[k + 1], &zi, &zr);
      ptab[tid] = make_float4(c, s, zr, zi);
    }
    __syncthreads();

    {  // P0: layer-0 qubits 0-3 straight from cached regs
      float ar[16], ai[16];
#pragma unroll
      for (int r = 0; r < 16; ++r) { ar[r] = encR[r]; ai[r] = encI[r]; }
      applyRyRz4(ar, ai, &ptab[0]);
      ldsWrite16<0>(sRe, sIm, tid, ar, ai, 0);
      __syncthreads();
    }
    projPass<1>(sRe, sIm, tid, 0, &ptab[4]);
    projPass<2>(sRe, sIm, tid, 0, &ptab[8]);
    projPass<0>(sRe, sIm, tid, 3, &ptab[12]);  // layer-0 ladder folded into read
    projPass<1>(sRe, sIm, tid, 0, &ptab[16]);

    float feat[12];
    projFinal(sRe, sIm, tid, &ptab[20], feat);
#pragma unroll
    for (int q = 0; q < 12; ++q) feat[q] = waveReduce(feat[q]);
    int wid = tid >> 6;
    if ((tid & 63) == 0) {
#pragma unroll
      for (int q = 0; q < 12; ++q) red[wid][q] = feat[q];
    }
    __syncthreads();
    if (tid < 12) {
      float v = red[0][tid] + red[1][tid] + red[2][tid] + red[3][tid];
      float* dst;
      if (which == 1)      dst = wsK + (((h << 3) + b) * 64 + t) * 12;
      else if (which == 2) dst = wsV + (((h << 3) + b) * 64 + t) * 12;
      else                 dst = wsQ + ((h << 3) + b) * 12;
      dst[tid] = v;
    }
    __syncthreads();
  }
}

__global__ __launch_bounds__(64) void qhead_kernel(
    const float* __restrict__ ws,
    const float* __restrict__ W1, const float* __restrict__ b1,
    const float* __restrict__ W2, const float* __restrict__ b2,
    float* __restrict__ out) {
  __shared__ float feats[24];
  __shared__ float hdn[48];
  const int b = blockIdx.x;
  const int lane = threadIdx.x;  // 64 = one wave = one key position s
  const float* Kf = ws;
  const float* Vf = ws + 12288;
  const float* Qf = ws + 24576;
  for (int h = 0; h < 2; ++h) {
    const float* q  = Qf + ((h << 3) + b) * 12;
    const float* kr = Kf + ((((h << 3) + b) << 6) + lane) * 12;
    float dot = 0.f;
#pragma unroll
    for (int d = 0; d < 12; ++d) dot += q[d] * kr[d];
    dot *= 0.288675134594812882f;  // 1/sqrt(12); mask row 63 is all-zero
    float mx = dot;
#pragma unroll
    for (int off = 32; off; off >>= 1) mx = fmaxf(mx, __shfl_xor(mx, off, 64));
    float e = expf(dot - mx);
    float se = e;
#pragma unroll
    for (int off = 32; off; off >>= 1) se += __shfl_xor(se, off, 64);
    float a = e / se;
    const float* vr = Vf + ((((h << 3) + b) << 6) + lane) * 12;
#pragma unroll
    for (int d = 0; d < 12; ++d) {
      float v = a * vr[d];
#pragma unroll
      for (int off = 32; off; off >>= 1) v += __shfl_xor(v, off, 64);
      if (lane == 0) feats[h * 12 + d] = v;
    }
  }
  __syncthreads();
  if (lane < 48) {
    float acc = b1[lane];
#pragma unroll
    for (int f = 0; f < 24; ++f) acc += feats[f] * W1[f * 48 + lane];
    hdn[lane] = 0.5f * acc * (1.0f + erff(acc * 0.70710678118654752440f));  // exact gelu
  }
  __syncthreads();
  if (lane < 4) {
    float acc = b2[lane];
#pragma unroll
    for (int k = 0; k < 48; ++k) acc += hdn[k] * W2[k * 4 + lane];
    out[(b << 2) | lane] = acc;
  }
}

extern "C" void kernel_launch(void* const* d_in, const int* in_sizes, int n_in,
                              void* d_out, int out_size, void* d_ws, size_t ws_size,
                              hipStream_t stream) {
  const float* seq     = (const float*)d_in[0];
  const float* resp    = (const float*)d_in[1];
  const float* hparams = (const float*)d_in[2];
  const float* W1      = (const float*)d_in[3];
  const float* b1      = (const float*)d_in[4];
  const float* W2      = (const float*)d_in[5];
  const float* b2      = (const float*)d_in[6];
  float* out = (float*)d_out;
  float* ws  = (float*)d_ws;  // needs 24768 floats (~99 KB)

  hipLaunchKernelGGL(qstates_kernel, dim3(512), dim3(256), 0, stream, seq, resp, hparams, ws);
  hipLaunchKernelGGL(qhead_kernel, dim3(8), dim3(64), 0, stream, ws, W1, b1, W2, b2, out);
}

// Round 2
// 147.891 us; speedup vs baseline: 1.2367x; 1.2367x over previous
//
#include <hip/hip_runtime.h>
#include <hip/hip_bf16.h>

// 12-qubit statevector pipeline, fp32.
// Split path (ws >= ~17MB):
//   enc_kernel  : 512 blocks, encode reservoir state -> ws (CX_LONG folded).
//   proj_kernel : 2064 blocks (one projection each), 12-dim features -> ws.
//   qhead_kernel: attention last-row + MLP -> d_out.
// Fallback monolithic path if ws is small (round-1 structure).

#define PADDED 4224  // 4096 + 4096/32 padding

__device__ __forceinline__ int PD(int j) { return j + (j >> 5); }

// mode 0: identity; 1: encode ladder+ring read map; 2: CX_LONG; 3: ladder only
__device__ __forceinline__ int mapIdx(int j, int mode) {
  if (mode == 1) { int k = j ^ ((j >> 11) & 1); return k ^ ((k & 0x7FF) << 1); }
  if (mode == 2) { return j ^ ((j & 1) << 11); }
  if (mode == 3) { return j ^ ((j & 0x7FF) << 1); }
  return j;
}

template <int L>
__device__ __forceinline__ int layoutIdx(int tid, int r) {
  if constexpr (L == 0) return (tid << 4) | r;                                   // bits 0-3 local
  else if constexpr (L == 1) return ((tid & 0xF0) << 4) | (r << 4) | (tid & 15); // bits 4-7 local
  else return (r << 8) | tid;                                                    // bits 8-11 local
}

template <int L>
__device__ __forceinline__ void ldsRead16(const float* sR, const float* sI, int tid, int mode,
                                          float ar[16], float ai[16]) {
#pragma unroll
  for (int r = 0; r < 16; ++r) {
    int j = layoutIdx<L>(tid, r);
    int a = PD(mapIdx(j, mode));
    ar[r] = sR[a]; ai[r] = sI[a];
  }
}

template <int L>
__device__ __forceinline__ void ldsWrite16(float* sR, float* sI, int tid,
                                           const float ar[16], const float ai[16], int czmask) {
#pragma unroll
  for (int r = 0; r < 16; ++r) {
    int j = layoutIdx<L>(tid, r);
    float vr = ar[r], vi = ai[r];
    if (czmask) {
      float sg = (__popc((j & (j >> 1)) & czmask) & 1) ? -1.0f : 1.0f;
      vr *= sg; vi *= sg;
    }
    int a = PD(j);
    sR[a] = vr; sI[a] = vi;
  }
}

// 4 U3 gates on local bits 0..3; u00 is real (= cos t/2), exploit u[1]==0.
// ut[b] = {u00r, 0, u01r, u01i, u10r, u10i, u11r, u11i}
__device__ __forceinline__ void applyU34(float ar[16], float ai[16], const float (*ut)[8]) {
#pragma unroll
  for (int b = 0; b < 4; ++b) {
    const float* u = ut[b];
    float u00r = u[0];
    float u01r = u[2], u01i = u[3];
    float u10r = u[4], u10i = u[5], u11r = u[6], u11i = u[7];
#pragma unroll
    for (int m = 0; m < 8; ++m) {
      int p0 = ((m >> b) << (b + 1)) | (m & ((1 << b) - 1));
      int p1 = p0 | (1 << b);
      float x0r = ar[p0], x0i = ai[p0], x1r = ar[p1], x1i = ai[p1];
      ar[p0] = u00r * x0r + u01r * x1r - u01i * x1i;
      ai[p0] = u00r * x0i + u01r * x1i + u01i * x1r;
      ar[p1] = u10r * x0r - u10i * x0i + u11r * x1r - u11i * x1i;
      ai[p1] = u10r * x0i + u10i * x0r + u11r * x1i + u11i * x1r;
    }
  }
}

// 4 fused RY+RZ gates, global phase dropped: G = diag(1, e^{i phi}) * RY(theta)
// gt[b] = {cos t/2, sin t/2, cos phi, sin phi}; 12 VALU ops/pair.
__device__ __forceinline__ void applyRyRz4(float ar[16], float ai[16], const float4* gt) {
#pragma unroll
  for (int b = 0; b < 4; ++b) {
    float4 g = gt[b];
    float c = g.x, s = g.y, zr = g.z, zi = g.w;
#pragma unroll
    for (int m = 0; m < 8; ++m) {
      int p0 = ((m >> b) << (b + 1)) | (m & ((1 << b) - 1));
      int p1 = p0 | (1 << b);
      float x0r = ar[p0], x0i = ai[p0], x1r = ar[p1], x1i = ai[p1];
      float n0r = c * x0r - s * x1r;
      float n0i = c * x0i - s * x1i;
      float wr  = s * x0r + c * x1r;
      float wi  = s * x0i + c * x1i;
      ar[p0] = n0r;              ai[p0] = n0i;
      ar[p1] = wr * zr - wi * zi; ai[p1] = wr * zi + wi * zr;
    }
  }
}

template <int L>
__device__ __forceinline__ void encPass(float* sR, float* sI, int tid, int mode,
                                        const float (*ut)[8], int czmask) {
  float ar[16], ai[16];
  ldsRead16<L>(sR, sI, tid, mode, ar, ai);
  if (mode != 0) __syncthreads();   // perm reads cross thread sets: drain before writes
  applyU34(ar, ai, ut);
  ldsWrite16<L>(sR, sI, tid, ar, ai, czmask);
  __syncthreads();
}

template <int L>
__device__ __forceinline__ void projPass(float* sR, float* sI, int tid, int mode, const float4* gt) {
  float ar[16], ai[16];
  ldsRead16<L>(sR, sI, tid, mode, ar, ai);
  if (mode != 0) __syncthreads();
  applyRyRz4(ar, ai, gt);
  ldsWrite16<L>(sR, sI, tid, ar, ai, 0);
  __syncthreads();
}

// Final projection pass: gates on qubits 8-11 of layer 1, then fold the trailing
// CX ladder into the Z-sign via M^{-1} = prefix-XOR; accumulate 12 features.
__device__ __forceinline__ void projFinal(const float* sR, const float* sI, int tid,
                                          const float4* gt, float feat[12]) {
  float ar[16], ai[16];
#pragma unroll
  for (int r = 0; r < 16; ++r) {
    int a = PD((r << 8) | tid);
    ar[r] = sR[a]; ai[r] = sI[a];
  }
  applyRyRz4(ar, ai, gt);
  float sp = 0.f, f0 = 0.f, f1 = 0.f, f2 = 0.f, f3 = 0.f;
  int pt = __popc(tid) & 1;  // parity of j bits 0..7
#pragma unroll
  for (int r = 0; r < 16; ++r) {
    float p = ar[r] * ar[r] + ai[r] * ai[r];
    sp += p;
    int tr = r ^ (r << 1); tr ^= (tr << 2);  // 4-bit prefix-xor of r
    f0 += ((pt ^ ((tr >> 3) & 1)) ? -p : p);
    f1 += ((pt ^ ((tr >> 2) & 1)) ? -p : p);
    f2 += ((pt ^ ((tr >> 1) & 1)) ? -p : p);
    f3 += ((pt ^ (tr & 1)) ? -p : p);
  }
  feat[0] = f0; feat[1] = f1; feat[2] = f2; feat[3] = f3;
  int tt = tid ^ (tid << 1); tt ^= (tt << 2); tt ^= (tt << 4);  // 8-bit prefix-xor of tid
#pragma unroll
  for (int q = 4; q < 12; ++q)
    feat[q] = ((tt >> (11 - q)) & 1) ? -sp : sp;
}

__device__ __forceinline__ float waveReduce(float v) {
#pragma unroll
  for (int off = 32; off; off >>= 1) v += __shfl_xor(v, off, 64);
  return v;
}

// ---- shared setup helpers ----

__device__ __forceinline__ void buildQtab(float4* qtab, int tid, float x) {
  const float PI = 3.14159265358979323846f;
  const float RS2 = 0.70710678118654752440f;
  if (tid < 12) {
    int i = tid;
    float th = x * PI * (float)(i + 1) / 12.0f;
    float ph = x * PI / (float)(i + 1);
    float s, c;  sincosf(0.5f * th, &s, &c);
    float zi, zr; sincosf(0.5f * ph, &zi, &zr);
    float k0 = (c - s) * RS2, k1 = (c + s) * RS2;
    qtab[i] = make_float4(k0 * zr, -k0 * zi, k1 * zr, k1 * zi);
  }
}

__device__ __forceinline__ void buildUtab(float (*utab)[8], int tid, const float* resp) {
  if (tid >= 64 && tid < 100) {
    int i = tid - 64;
    const float* rp = resp + i * 3;
    float st, ct;  sincosf(0.5f * rp[0], &st, &ct);
    float sp2, cp; sincosf(rp[1], &sp2, &cp);
    float sl, cl;  sincosf(rp[2], &sl, &cl);
    float spl, cpl; sincosf(rp[1] + rp[2], &spl, &cpl);
    float* u = utab[i];
    u[0] = ct;       u[1] = 0.0f;
    u[2] = -cl * st; u[3] = -sl * st;
    u[4] = cp * st;  u[5] = sp2 * st;
    u[6] = cpl * ct; u[7] = spl * ct;
  }
}

// E0: product state directly (init RY/RZ are all single-qubit on |+>^12)
__device__ __forceinline__ void initProduct(float* sRe, float* sIm, int tid, const float4* qtab) {
  float pr, pi;
  {
    float4 g = qtab[4];
    int sb = tid & 1;
    pr = sb ? g.z : g.x; pi = sb ? g.w : g.y;
  }
#pragma unroll
  for (int q = 5; q < 12; ++q) {
    float4 g = qtab[q];
    int sb = (tid >> (q - 4)) & 1;
    float fr = sb ? g.z : g.x, fi = sb ? g.w : g.y;
    float nr = pr * fr - pi * fi;
    pi = pr * fi + pi * fr; pr = nr;
  }
  float4 g0 = qtab[0], g1 = qtab[1], g2 = qtab[2], g3 = qtab[3];
  float c01r[4], c01i[4], c23r[4], c23i[4];
#pragma unroll
  for (int i2 = 0; i2 < 4; ++i2) {
    float f0r = (i2 & 1) ? g0.z : g0.x, f0i = (i2 & 1) ? g0.w : g0.y;
    float f1r = (i2 & 2) ? g1.z : g1.x, f1i = (i2 & 2) ? g1.w : g1.y;
    c01r[i2] = f0r * f1r - f0i * f1i; c01i[i2] = f0r * f1i + f0i * f1r;
    float f2r = (i2 & 1) ? g2.z : g2.x, f2i = (i2 & 1) ? g2.w : g2.y;
    float f3r = (i2 & 2) ? g3.z : g3.x, f3i = (i2 & 2) ? g3.w : g3.y;
    c23r[i2] = f2r * f3r - f2i * f3i; c23i[i2] = f2r * f3i + f2i * f3r;
  }
#pragma unroll
  for (int r = 0; r < 16; ++r) {
    float lr = c01r[r & 3] * c23r[r >> 2] - c01i[r & 3] * c23i[r >> 2];
    float li = c01r[r & 3] * c23i[r >> 2] + c01i[r & 3] * c23r[r >> 2];
    int a = PD((tid << 4) | r);
    sRe[a] = pr * lr - pi * li;
    sIm[a] = pr * li + pi * lr;
  }
}

__device__ __forceinline__ void buildPtab(float4* ptab, int tid, const float* hp) {
  if (tid < 24) {
    int k = tid * 2;
    float s, c;  sincosf(0.5f * hp[k], &s, &c);
    float zi, zr; sincosf(hp[k + 1], &zi, &zr);  // full angle: global phase dropped
    ptab[tid] = make_float4(c, s, zr, zi);
  }
}

// ================= SPLIT PATH =================

// Kernel A: encode -> global (CX_LONG after layer 3 folded into store index).
__global__ __launch_bounds__(256, 2) void enc_kernel(
    const float* __restrict__ seq, const float* __restrict__ resp,
    float* __restrict__ wsStates) {
  __shared__ float sRe[PADDED], sIm[PADDED];
  __shared__ float4 qtab[12];
  __shared__ float utab[36][8];

  const int tid = threadIdx.x;
  const int blk = blockIdx.x;          // = state index s = b*64 + t
  const float x = seq[blk];

  buildQtab(qtab, tid, x);
  buildUtab(utab, tid, resp);
  __syncthreads();

  initProduct(sRe, sIm, tid, qtab);
  __syncthreads();

  // layers 1..3 of 12 U3 + CZ; perms folded into read maps
  encPass<0>(sRe, sIm, tid, 1, &utab[0], 0);
  encPass<1>(sRe, sIm, tid, 0, &utab[4], 0);
  encPass<2>(sRe, sIm, tid, 0, &utab[8], 0x555);
  encPass<0>(sRe, sIm, tid, 2, &utab[12], 0);
  encPass<1>(sRe, sIm, tid, 0, &utab[16], 0);
  encPass<2>(sRe, sIm, tid, 0, &utab[20], 0x2AA);
  encPass<0>(sRe, sIm, tid, 2, &utab[24], 0);
  encPass<1>(sRe, sIm, tid, 0, &utab[28], 0);

  // final pass: gates 8-11 (layout2) + CZ(0x555), store with CX_LONG fold
  {
    float ar[16], ai[16];
    ldsRead16<2>(sRe, sIm, tid, 0, ar, ai);
    applyU34(ar, ai, &utab[32]);
    float* gR = wsStates + (size_t)blk * 8192;
    float* gI = gR + 4096;
#pragma unroll
    for (int r = 0; r < 16; ++r) {
      int j = (r << 8) | tid;
      float sg = (__popc((j & (j >> 1)) & 0x555) & 1) ? -1.0f : 1.0f;
      int g = j ^ ((j & 1) << 11);  // involution
      gR[g] = sg * ar[r];
      gI[g] = sg * ai[r];
    }
  }
}

// Kernel B: one projection per block.
__global__ __launch_bounds__(256, 4) void proj_kernel(
    const float* __restrict__ wsStates, const float* __restrict__ hparams,
    float* __restrict__ featBase) {
  __shared__ float sRe[PADDED], sIm[PADDED];
  __shared__ float4 ptab[24];
  __shared__ float red[4][12];

  const int tid = threadIdx.x;
  const int bid = blockIdx.x;
  int h, which, s;
  if (bid < 2048) { s = bid >> 2; int pp = bid & 3; h = pp >> 1; which = 1 + (pp & 1); }
  else            { int i = bid - 2048; h = i & 1; s = (((i >> 1) << 6) | 63); which = 0; }
  const int b = s >> 6, t = s & 63;

  buildPtab(ptab, tid, hparams + (h * 3 + which) * 48);

  // coalesced load of the encoded state: thread owns j = 16*tid .. 16*tid+15
  float ar[16], ai[16];
  const float4* pR = (const float4*)(wsStates + (size_t)s * 8192 + (tid << 4));
  const float4* pI = (const float4*)(wsStates + (size_t)s * 8192 + 4096 + (tid << 4));
#pragma unroll
  for (int k = 0; k < 4; ++k) {
    float4 vr = pR[k], vi = pI[k];
    ar[4 * k] = vr.x; ar[4 * k + 1] = vr.y; ar[4 * k + 2] = vr.z; ar[4 * k + 3] = vr.w;
    ai[4 * k] = vi.x; ai[4 * k + 1] = vi.y; ai[4 * k + 2] = vi.z; ai[4 * k + 3] = vi.w;
  }
  __syncthreads();  // ptab ready

  // P0: layer-0 qubits 0-3 straight from regs
  applyRyRz4(ar, ai, &ptab[0]);
  ldsWrite16<0>(sRe, sIm, tid, ar, ai, 0);
  __syncthreads();

  projPass<1>(sRe, sIm, tid, 0, &ptab[4]);
  projPass<2>(sRe, sIm, tid, 0, &ptab[8]);
  projPass<0>(sRe, sIm, tid, 3, &ptab[12]);  // layer-0 ladder folded into read
  projPass<1>(sRe, sIm, tid, 0, &ptab[16]);

  float feat[12];
  projFinal(sRe, sIm, tid, &ptab[20], feat);
#pragma unroll
  for (int q = 0; q < 12; ++q) feat[q] = waveReduce(feat[q]);
  int wid = tid >> 6;
  if ((tid & 63) == 0) {
#pragma unroll
    for (int q = 0; q < 12; ++q) red[wid][q] = feat[q];
  }
  __syncthreads();
  if (tid < 12) {
    float v = red[0][tid] + red[1][tid] + red[2][tid] + red[3][tid];
    float* dst;
    if (which == 1)      dst = featBase + (((h << 3) + b) * 64 + t) * 12;
    else if (which == 2) dst = featBase + 12288 + (((h << 3) + b) * 64 + t) * 12;
    else                 dst = featBase + 24576 + ((h << 3) + b) * 12;
    dst[tid] = v;
  }
}

// ================= MONOLITHIC FALLBACK =================

__global__ __launch_bounds__(256, 2) void qstates_mono(
    const float* __restrict__ seq, const float* __restrict__ resp,
    const float* __restrict__ hparams, float* __restrict__ featBase) {
  __shared__ float sRe[PADDED], sIm[PADDED];
  __shared__ float4 qtab[12];
  __shared__ float utab[36][8];
  __shared__ float4 ptab[24];
  __shared__ float red[4][12];

  const int tid = threadIdx.x;
  const int blk = blockIdx.x;
  const int b = blk >> 6;
  const int t = blk & 63;
  const float x = seq[blk];

  buildQtab(qtab, tid, x);
  buildUtab(utab, tid, resp);
  __syncthreads();
  initProduct(sRe, sIm, tid, qtab);
  __syncthreads();

  for (int l = 0; l < 3; ++l) {
    int czm = (l & 1) ? 0x2AA : 0x555;
    encPass<0>(sRe, sIm, tid, (l == 0) ? 1 : 2, &utab[l * 12], 0);
    encPass<1>(sRe, sIm, tid, 0, &utab[l * 12 + 4], 0);
    encPass<2>(sRe, sIm, tid, 0, &utab[l * 12 + 8], czm);
  }

  float encR[16], encI[16];
#pragma unroll
  for (int r = 0; r < 16; ++r) {
    int j = (tid << 4) | r;
    int a = PD(j ^ ((j & 1) << 11));
    encR[r] = sRe[a]; encI[r] = sIm[a];
  }

  const int nproj = (t == 63) ? 6 : 4;
  for (int pj = 0; pj < nproj; ++pj) {
    int h, which;
    if (pj < 4) { h = pj >> 1; which = (pj & 1) ? 2 : 1; }
    else        { h = pj - 4;  which = 0; }
    buildPtab(ptab, tid, hparams + (h * 3 + which) * 48);
    __syncthreads();

    float ar[16], ai[16];
#pragma unroll
    for (int r = 0; r < 16; ++r) { ar[r] = encR[r]; ai[r] = encI[r]; }
    applyRyRz4(ar, ai, &ptab[0]);
    ldsWrite16<0>(sRe, sIm, tid, ar, ai, 0);
    __syncthreads();
    projPass<1>(sRe, sIm, tid, 0, &ptab[4]);
    projPass<2>(sRe, sIm, tid, 0, &ptab[8]);
    projPass<0>(sRe, sIm, tid, 3, &ptab[12]);
    projPass<1>(sRe, sIm, tid, 0, &ptab[16]);

    float feat[12];
    projFinal(sRe, sIm, tid, &ptab[20], feat);
#pragma unroll
    for (int q = 0; q < 12; ++q) feat[q] = waveReduce(feat[q]);
    int wid = tid >> 6;
    if ((tid & 63) == 0) {
#pragma unroll
      for (int q = 0; q < 12; ++q) red[wid][q] = feat[q];
    }
    __syncthreads();
    if (tid < 12) {
      float v = red[0][tid] + red[1][tid] + red[2][tid] + red[3][tid];
      float* dst;
      if (which == 1)      dst = featBase + (((h << 3) + b) * 64 + t) * 12;
      else if (which == 2) dst = featBase + 12288 + (((h << 3) + b) * 64 + t) * 12;
      else                 dst = featBase + 24576 + ((h << 3) + b) * 12;
      dst[tid] = v;
    }
    __syncthreads();
  }
}

// ================= HEAD =================

__global__ __launch_bounds__(64) void qhead_kernel(
    const float* __restrict__ featBase,
    const float* __restrict__ W1, const float* __restrict__ b1,
    const float* __restrict__ W2, const float* __restrict__ b2,
    float* __restrict__ out) {
  __shared__ float feats[24];
  __shared__ float hdn[48];
  const int b = blockIdx.x;
  const int lane = threadIdx.x;  // 64 = one wave = one key position s
  const float* Kf = featBase;
  const float* Vf = featBase + 12288;
  const float* Qf = featBase + 24576;
  for (int h = 0; h < 2; ++h) {
    const float* q  = Qf + ((h << 3) + b) * 12;
    const float* kr = Kf + ((((h << 3) + b) << 6) + lane) * 12;
    float dot = 0.f;
#pragma unroll
    for (int d = 0; d < 12; ++d) dot += q[d] * kr[d];
    dot *= 0.288675134594812882f;  // 1/sqrt(12); mask row 63 is all-zero
    float mx = dot;
#pragma unroll
    for (int off = 32; off; off >>= 1) mx = fmaxf(mx, __shfl_xor(mx, off, 64));
    float e = expf(dot - mx);
    float se = e;
#pragma unroll
    for (int off = 32; off; off >>= 1) se += __shfl_xor(se, off, 64);
    float a = e / se;
    const float* vr = Vf + ((((h << 3) + b) << 6) + lane) * 12;
#pragma unroll
    for (int d = 0; d < 12; ++d) {
      float v = a * vr[d];
#pragma unroll
      for (int off = 32; off; off >>= 1) v += __shfl_xor(v, off, 64);
      if (lane == 0) feats[h * 12 + d] = v;
    }
  }
  __syncthreads();
  if (lane < 48) {
    float acc = b1[lane];
#pragma unroll
    for (int f = 0; f < 24; ++f) acc += feats[f] * W1[f * 48 + lane];
    hdn[lane] = 0.5f * acc * (1.0f + erff(acc * 0.70710678118654752440f));  // exact gelu
  }
  __syncthreads();
  if (lane < 4) {
    float acc = b2[lane];
#pragma unroll
    for (int k = 0; k < 48; ++k) acc += hdn[k] * W2[k * 4 + lane];
    out[(b << 2) | lane] = acc;
  }
}

extern "C" void kernel_launch(void* const* d_in, const int* in_sizes, int n_in,
                              void* d_out, int out_size, void* d_ws, size_t ws_size,
                              hipStream_t stream) {
  const float* seq     = (const float*)d_in[0];
  const float* resp    = (const float*)d_in[1];
  const float* hparams = (const float*)d_in[2];
  const float* W1      = (const float*)d_in[3];
  const float* b1      = (const float*)d_in[4];
  const float* W2      = (const float*)d_in[5];
  const float* b2      = (const float*)d_in[6];
  float* out = (float*)d_out;
  float* ws  = (float*)d_ws;

  const size_t needSplit = ((size_t)512 * 8192 + 24768) * sizeof(float);  // ~16.9 MB
  if (ws_size >= needSplit) {
    float* wsStates = ws;
    float* featBase = ws + (size_t)512 * 8192;
    hipLaunchKernelGGL(enc_kernel, dim3(512), dim3(256), 0, stream, seq, resp, wsStates);
    hipLaunchKernelGGL(proj_kernel, dim3(2064), dim3(256), 0, stream, wsStates, hparams, featBase);
    hipLaunchKernelGGL(qhead_kernel, dim3(8), dim3(64), 0, stream, featBase, W1, b1, W2, b2, out);
  } else {
    hipLaunchKernelGGL(qstates_mono, dim3(512), dim3(256), 0, stream, seq, resp, hparams, ws);
    hipLaunchKernelGGL(qhead_kernel, dim3(8), dim3(64), 0, stream, ws, W1, b1, W2, b2, out);
  }
}